// Round 7
// baseline (171.383 us; speedup 1.0000x reference)
//
#include <hip/hip_runtime.h>

#define NROWS 4096
#define DDIM  256
#define K2    768          // augmented K: [hi|hi|lo] x [hi|lo|hi]
#define MARGIN 0.1f
#define GRID_MAIN 512      // 8 XCD slots x (4 i-tiles x 16 j-tiles)

typedef __attribute__((ext_vector_type(4)))  _Float16 half4;
typedef __attribute__((ext_vector_type(8)))  _Float16 half8;
typedef __attribute__((ext_vector_type(16))) float    floatx16;

__device__ inline void load_lds16(const void* g, void* l) {
  __builtin_amdgcn_global_load_lds((const __attribute__((address_space(1))) void*)g,
                                   (__attribute__((address_space(3))) void*)l,
                                   16, 0, 0);
}

// ---- Kernel 1 (R4-verified): pack A'=[Vhi|Vhi|Vlo], B'=[Thi|Tlo|Thi]; diag; zero accs ----
__global__ __launch_bounds__(256) void convert_diag_kernel(
    const float* __restrict__ v, const float* __restrict__ t,
    _Float16* __restrict__ Ap, _Float16* __restrict__ Bp,
    float* __restrict__ diag, int* __restrict__ rank, float* __restrict__ sums,
    int* __restrict__ done) {
  const int w    = threadIdx.x >> 6;
  const int lane = threadIdx.x & 63;
  const int row  = blockIdx.x * 4 + w;
  const size_t base = (size_t)row * DDIM;
  const float4 a = ((const float4*)(v + base))[lane];
  const float4 b = ((const float4*)(t + base))[lane];
  half4 ah, al, bh, bl;
  ah.x = (_Float16)a.x; al.x = (_Float16)(a.x - (float)ah.x);
  ah.y = (_Float16)a.y; al.y = (_Float16)(a.y - (float)ah.y);
  ah.z = (_Float16)a.z; al.z = (_Float16)(a.z - (float)ah.z);
  ah.w = (_Float16)a.w; al.w = (_Float16)(a.w - (float)ah.w);
  bh.x = (_Float16)b.x; bl.x = (_Float16)(b.x - (float)bh.x);
  bh.y = (_Float16)b.y; bl.y = (_Float16)(b.y - (float)bh.y);
  bh.z = (_Float16)b.z; bl.z = (_Float16)(b.z - (float)bh.z);
  bh.w = (_Float16)b.w; bl.w = (_Float16)(b.w - (float)bh.w);
  _Float16* ar = Ap + (size_t)row * K2;
  _Float16* br = Bp + (size_t)row * K2;
  *(half4*)(ar + 4 * lane)       = ah;
  *(half4*)(ar + 256 + 4 * lane) = ah;
  *(half4*)(ar + 512 + 4 * lane) = al;
  *(half4*)(br + 4 * lane)       = bh;
  *(half4*)(br + 256 + 4 * lane) = bl;
  *(half4*)(br + 512 + 4 * lane) = bh;
  float s = a.x*b.x + a.y*b.y + a.z*b.z + a.w*b.w;
  #pragma unroll
  for (int off = 32; off; off >>= 1) s += __shfl_down(s, off);
  if (lane == 0) { diag[row] = s; rank[row] = 0; }
  if (blockIdx.x == 0 && threadIdx.x < 4) {
    if (threadIdx.x < 2) sums[threadIdx.x] = 0.f;
    if (threadIdx.x == 2) *done = 0;
  }
}

// ---- Kernel 2: XCD-partitioned f16 GEMM (256x128 tile, BK=64, DMA staging)
//      + fused epilogue + last-block finale ----
// Partition (FIXED vs R6): bid 0..511; xcd = bid&7; loc = bid>>3 in [0,64).
// XCD owns i-rows [(xcd>>1)*1024, +1024) x j-cols [(xcd&1)*2048, +2048):
//   i-tile = loc&3 (4 x 256), j-tile = loc>>2 in [0,16) (16 x 128).
// Per-XCD unique data 4.5 MB ~= its L2; 512 tiles covered exactly once.
__global__ __launch_bounds__(256, 2) void main_kernel(
    const _Float16* __restrict__ Ap, const _Float16* __restrict__ Bp,
    const float* __restrict__ diag, float* __restrict__ sums,
    int* __restrict__ rank, int* __restrict__ done, float* __restrict__ out) {
  __shared__ __align__(16) _Float16 As[256 * 64];   // 32 KB
  __shared__ __align__(16) _Float16 Bs[128 * 64];   // 16 KB
  __shared__ float sdi[256];
  __shared__ float sdj[128];
  __shared__ int   is_last;

  const int tid  = threadIdx.x;
  const int w    = tid >> 6;
  const int lane = tid & 63;

  const int bid = blockIdx.x;
  const int xcd = bid & 7;
  const int loc = bid >> 3;                       // 0..63
  const int i0  = (xcd >> 1) * 1024 + (loc & 3) * 256;
  const int j0  = (xcd & 1) * 2048 + (loc >> 2) * 128;   // loc>>2 in [0,16)

  // staging maps (R4-verified): q = r*256+tid; row=q>>3; global chunk=(q&7)^(row&7)
  const _Float16* gA[8];
  _Float16* lA[8];
  #pragma unroll
  for (int r = 0; r < 8; ++r) {
    const int q   = r * 256 + tid;
    const int row = q >> 3;
    const int chg = (q & 7) ^ (row & 7);
    gA[r] = Ap + (size_t)(i0 + row) * K2 + chg * 8;
    lA[r] = As + (r * 256 + w * 64) * 8;          // wave-uniform; HW adds lane*16
  }
  const _Float16* gB[4];
  _Float16* lB[4];
  #pragma unroll
  for (int r = 0; r < 4; ++r) {
    const int q   = r * 256 + tid;
    const int row = q >> 3;
    const int chg = (q & 7) ^ (row & 7);
    gB[r] = Bp + (size_t)(j0 + row) * K2 + chg * 8;
    lB[r] = Bs + (r * 256 + w * 64) * 8;
  }

  floatx16 acc[4][2];
  #pragma unroll
  for (int mt = 0; mt < 4; ++mt)
    #pragma unroll
    for (int nt = 0; nt < 2; ++nt)
      #pragma unroll
      for (int r = 0; r < 16; ++r) acc[mt][nt][r] = 0.f;

  const int mw    = (w >> 1) * 128;
  const int nw    = (w & 1) * 64;
  const int rL    = lane & 31;
  const int khsel = lane >> 5;

  #pragma unroll 1
  for (int slab = 0; slab < K2 / 64; ++slab) {
    __syncthreads();   // previous compute done reading LDS
    #pragma unroll
    for (int r = 0; r < 8; ++r) load_lds16(gA[r] + slab * 64, lA[r]);
    #pragma unroll
    for (int r = 0; r < 4; ++r) load_lds16(gB[r] + slab * 64, lB[r]);
    __syncthreads();   // staging complete (compiler drains vmcnt)

    #pragma unroll
    for (int ks = 0; ks < 4; ++ks) {
      const int lc = ks * 2 + khsel;
      half8 af[4], bf[2];
      #pragma unroll
      for (int mt = 0; mt < 4; ++mt) {
        const int row = mw + mt * 32 + rL;
        af[mt] = *(const half8*)&As[row * 64 + (lc ^ (row & 7)) * 8];
      }
      #pragma unroll
      for (int nt = 0; nt < 2; ++nt) {
        const int row = nw + nt * 32 + rL;
        bf[nt] = *(const half8*)&Bs[row * 64 + (lc ^ (row & 7)) * 8];
      }
      #pragma unroll
      for (int mt = 0; mt < 4; ++mt)
        #pragma unroll
        for (int nt = 0; nt < 2; ++nt)
          acc[mt][nt] = __builtin_amdgcn_mfma_f32_32x32x16_f16(af[mt], bf[nt], acc[mt][nt], 0, 0, 0);
    }
  }

  // ---- epilogue (R2-verified): col=lane&31, row=(reg&3)+8*(reg>>2)+4*(lane>>5) ----
  if (tid < 128) { sdi[tid] = diag[i0 + tid]; sdj[tid] = diag[j0 + tid]; }
  else           { sdi[tid] = diag[i0 + tid]; }
  __syncthreads();

  float vt = 0.f, tv = 0.f;
  const int h = lane >> 5;
  #pragma unroll
  for (int mt = 0; mt < 4; ++mt) {
    const int rbase = mw + mt * 32;
    #pragma unroll
    for (int reg = 0; reg < 16; ++reg) {
      const int r  = (reg & 3) + 8 * (reg >> 2) + 4 * h;
      const int gi = i0 + rbase + r;
      const float di = sdi[rbase + r];
      unsigned long long b0 = 0, b1 = 0;
      #pragma unroll
      for (int nt = 0; nt < 2; ++nt) {
        const int cc = nw + nt * 32 + rL;
        const int gj = j0 + cc;
        const float s  = acc[mt][nt][reg];
        const float dj = sdj[cc];
        const bool ne = (gi != gj);
        if (ne) {
          vt += fmaxf(0.f, MARGIN - di + s);
          tv += fmaxf(0.f, MARGIN - dj + s);
        }
        const unsigned long long bb = __ballot(ne && (s > di));
        if (nt == 0) b0 = bb; else b1 = bb;
      }
      if (rL == 0) {
        const int cnt = h ? (int)(__popcll(b0 >> 32) + __popcll(b1 >> 32))
                          : (int)(__popcll(b0 & 0xFFFFFFFFull) + __popcll(b1 & 0xFFFFFFFFull));
        atomicAdd(&rank[gi], cnt);
      }
    }
  }
  #pragma unroll
  for (int off = 32; off; off >>= 1) {
    vt += __shfl_down(vt, off);
    tv += __shfl_down(tv, off);
  }
  if (lane == 0) {
    atomicAdd(&sums[0], vt);
    atomicAdd(&sums[1], tv);
  }

  // ---- fused finale (R4-verified): last-finishing block ----
  __threadfence();
  __syncthreads();
  if (tid == 0) is_last = (atomicAdd(done, 1) == GRID_MAIN - 1);
  __syncthreads();
  if (!is_last) return;

  int c1 = 0, c5 = 0, c10 = 0, cs = 0;
  for (int i = tid; i < NROWS; i += 256) {
    const int r = atomicAdd(&rank[i], 0);   // device-scope coherent read
    c1  += (r < 1);
    c5  += (r < 5);
    c10 += (r < 10);
    cs  += r;
  }
  #pragma unroll
  for (int off = 32; off; off >>= 1) {
    c1  += __shfl_down(c1, off);
    c5  += __shfl_down(c5, off);
    c10 += __shfl_down(c10, off);
    cs  += __shfl_down(cs, off);
  }
  __shared__ int s1[4], s5[4], s10[4], ssm[4];
  if ((tid & 63) == 0) { s1[w] = c1; s5[w] = c5; s10[w] = c10; ssm[w] = cs; }
  __syncthreads();
  if (tid == 0) {
    int a1 = 0, a5 = 0, a10 = 0, as = 0;
    #pragma unroll
    for (int k = 0; k < 4; ++k) { a1 += s1[k]; a5 += s5[k]; a10 += s10[k]; as += ssm[k]; }
    const float denom = 4096.0f * 4095.0f;
    out[0] = atomicAdd(&sums[0], 0.f) / denom;
    out[1] = atomicAdd(&sums[1], 0.f) / denom;
    out[2] = a1  / 4096.0f;
    out[3] = a5  / 4096.0f;
    out[4] = a10 / 4096.0f;
    out[5] = (float)as / 4096.0f;
  }
}

extern "C" void kernel_launch(void* const* d_in, const int* in_sizes, int n_in,
                              void* d_out, int out_size, void* d_ws, size_t ws_size,
                              hipStream_t stream) {
  const float* v = (const float*)d_in[0];
  const float* t = (const float*)d_in[1];
  float* out = (float*)d_out;

  // ws (>= 12.6 MB, proven by R3/R4 running Path A):
  // Ap 6MB | Bp 6MB | diag 16KB | rank 16KB | sums | done
  const size_t PACK = (size_t)NROWS * K2 * sizeof(_Float16);
  _Float16* Ap = (_Float16*)d_ws;
  _Float16* Bp = (_Float16*)((char*)d_ws + PACK);
  float* diag = (float*)((char*)d_ws + 2 * PACK);
  int*   rank = (int*)((char*)d_ws + 2 * PACK + NROWS * 4);
  float* sums = (float*)((char*)d_ws + 2 * PACK + 2 * (size_t)NROWS * 4);
  int*   done = (int*)((char*)d_ws + 2 * PACK + 2 * (size_t)NROWS * 4 + 64);

  hipLaunchKernelGGL(convert_diag_kernel, dim3(NROWS / 4), dim3(256), 0, stream,
                     v, t, Ap, Bp, diag, rank, sums, done);
  hipLaunchKernelGGL(main_kernel, dim3(GRID_MAIN), dim3(256), 0, stream,
                     Ap, Bp, diag, sums, rank, done, out);
}